// Round 2
// baseline (387.759 us; speedup 1.0000x reference)
//
#include <hip/hip_runtime.h>
#include <hip/hip_bf16.h>
#include <hip/hip_fp16.h>

#define DD    128
#define VOCAB 2048
#define KW    16640          // Wext row stride = 16384 (kron) + 256 (lin)
#define NRELS 7

typedef _Float16 f16;
typedef __attribute__((ext_vector_type(8))) _Float16 f16x8;
typedef __attribute__((ext_vector_type(4))) float    f32x4;

// flexible-dtype load: bf==1 -> bf16 storage, bf==0 -> f32 storage
__device__ __forceinline__ float lde(const void* p, size_t i, int bf) {
    if (bf) return (float)((const __hip_bfloat16*)p)[i];
    return ((const float*)p)[i];
}

// ---------------------------------------------------------------------------
// detect: classify storage dtype of float tensors by exponent-field sanity.
// True bf16 Gaussian weights (|x|~0.02): exponent field always in [90,160].
// f32-as-uint16: low halves ~uniform random -> essentially never all sane.
// ---------------------------------------------------------------------------
__global__ void detect_kernel(const unsigned short* __restrict__ wv, int* __restrict__ flag)
{
    if (threadIdx.x == 0 && blockIdx.x == 0) {
        int sane = 0;
        for (int i = 0; i < 64; ++i) {
            unsigned e = (wv[i] >> 7) & 0xFFu;
            if (e >= 90u && e <= 160u) ++sane;
        }
        *flag = (sane == 64) ? 1 : 0;
    }
}

// ---------------------------------------------------------------------------
// prep: convert all weights to f16 working copies.
// ---------------------------------------------------------------------------
__global__ void prep_kernel(const void* Wv, const void* bv, const void* Wcps, const void* bcps,
                            const void* Wcpst, const void* bcpst, const void* Wcpr, const void* bcpr,
                            const void* Wcprt, const void* bcprt, const void* Wsm, const void* bsm,
                            const int* __restrict__ flag,
                            f16* __restrict__ WvT, f16* __restrict__ Wext, f16* __restrict__ Wfin,
                            float* __restrict__ bias_lvl, float* __restrict__ bias_fin,
                            float* __restrict__ Wsm_f, float* __restrict__ bsm_f)
{
    const int bf = *flag;
    long idx = (long)blockIdx.x * 256 + threadIdx.x;
    const long nWvT = (long)VOCAB * DD;        // 262144
    const long nW   = (long)DD * KW;           // 2129920
    if (idx < nWvT) {
        int v = (int)(idx >> 7), d = (int)(idx & 127);
        WvT[idx] = (f16)(lde(Wv, (size_t)d * VOCAB + v, bf) + lde(bv, d, bf));
        return;
    }
    idx -= nWvT;
    if (idx < nW) {
        int n = (int)(idx / KW), k = (int)(idx - (long)n * KW);
        float val = (k < 16384) ? lde(Wcpst, (size_t)n * 16384 + k, bf)
                                : lde(Wcps,  (size_t)n * 256 + (k - 16384), bf);
        Wext[idx] = (f16)val;
        return;
    }
    idx -= nW;
    if (idx < nW) {
        int n = (int)(idx / KW), k = (int)(idx - (long)n * KW);
        float val = (k < 16384) ? lde(Wcprt, (size_t)n * 16384 + k, bf)
                                : lde(Wcpr,  (size_t)n * 256 + (k - 16384), bf);
        Wfin[idx] = (f16)val;
        return;
    }
    idx -= nW;
    if (idx < 128)            bias_lvl[idx] = lde(bcps, idx, bf) + lde(bcpst, idx, bf);
    else if (idx < 256)       bias_fin[idx - 128] = lde(bcpr, idx - 128, bf) + lde(bcprt, idx - 128, bf);
    else if (idx < 256 + 896) Wsm_f[idx - 256] = lde(Wsm, idx - 256, bf);
    else if (idx < 256 + 896 + NRELS) bsm_f[idx - 256 - 896] = lde(bsm, idx - 256 - 896, bf);
}

// ---------------------------------------------------------------------------
__global__ void embed_kernel(const int* __restrict__ ids,
                             const f16* __restrict__ WvT, f16* __restrict__ h0)
{
    int t = blockIdx.x * 256 + threadIdx.x;
    int row = t >> 4;
    int c = (t & 15) * 8;
    int id = ids[row];
    *(f16x8*)&h0[(size_t)row * DD + c] = *(const f16x8*)&WvT[(size_t)id * DD + c];
}

// ---------------------------------------------------------------------------
// GEMM over A_ext = [kron(l,r) | l | r] vs W (128 x 16640), split-K over
// kron rows i. Block tile 128x128, 4 waves (2x2 of 64x64). LDS = 64 KB.
// ---------------------------------------------------------------------------
__launch_bounds__(256)
__global__ void gemm_kernel(const f16* __restrict__ hin, const f16* __restrict__ W,
                            float* __restrict__ part, int Mrows, int S, int BI)
{
    __shared__ f16 Lt[128 * 128];       // 32 KB, phys block = cb ^ (row&15)
    __shared__ f16 Wb[2][16 * 512];     // 2 x 16 KB, 16 slots x (64 lanes x 8 halves)

    const int tid  = threadIdx.x;
    const int lane = tid & 63;
    const int wv   = tid >> 6;
    const int s    = blockIdx.x % S;
    const int mb   = blockIdx.x / S;
    const int m0   = mb * 128;
    const int i0   = s * BI;
    const int nI   = BI + ((s == 0) ? 2 : 0);
    const int NS   = nI * 2;

    #pragma unroll
    for (int it = 0; it < 8; ++it) {
        int c  = it * 256 + tid;            // 0..2047
        int mm = c >> 4;
        int cb = c & 15;
        f16x8 v = *(const f16x8*)&hin[(size_t)(2 * (m0 + mm)) * DD + cb * 8];
        *(f16x8*)&Lt[mm * 128 + ((cb ^ (mm & 15)) << 3)] = v;
    }

    const int wm   = (wv >> 1) * 64;
    const int wn   = (wv & 1) * 64;
    const int mrow = lane & 63 & 15;
    const int q    = (lane >> 4);

    f16x8 rf[4][4];
    #pragma unroll
    for (int mt = 0; mt < 4; ++mt)
        #pragma unroll
        for (int t = 0; t < 4; ++t)
            rf[mt][t] = *(const f16x8*)&hin[(size_t)(2 * (m0 + wm + mt * 16 + mrow) + 1) * DD + t * 32 + q * 8];

    auto stage = [&](int i, int h, int buf) {
        #pragma unroll
        for (int r = 0; r < 4; ++r) {
            int slot = r * 4 + wv;
            int nn   = (slot >> 1) * 16 + (lane & 15);
            int kk   = i * 128 + h * 64 + (slot & 1) * 32 + (lane >> 4) * 8;
            const f16* g = W + (size_t)nn * KW + kk;
            f16* l = &Wb[buf][slot * 512];
            __builtin_amdgcn_global_load_lds(
                (const __attribute__((address_space(1))) unsigned int*)g,
                (__attribute__((address_space(3))) unsigned int*)l, 16, 0, 0);
        }
    };
    auto imap = [&](int ii) { return (ii < BI) ? (i0 + ii) : (128 + ii - BI); };

    stage(imap(0), 0, 0);
    __syncthreads();

    f32x4 acc[4][4] = {};
    f16x8 lp[4];

#define TSTEP(T) {                                                                      \
    f16x8 bfr[4];                                                                       \
    _Pragma("unroll")                                                                   \
    for (int nt = 0; nt < 4; ++nt)                                                      \
        bfr[nt] = *(const f16x8*)&Wb[buf][((((wv & 1) * 4 + nt) * 2 + ((T) & 1)) * 512) + lane * 8]; \
    if (i < 128) {                                                                      \
        _Pragma("unroll")                                                               \
        for (int mt = 0; mt < 4; ++mt) {                                                \
            f16x8 a = lp[mt] * rf[mt][T];                                               \
            _Pragma("unroll")                                                           \
            for (int nt = 0; nt < 4; ++nt)                                              \
                acc[mt][nt] = __builtin_amdgcn_mfma_f32_16x16x32_f16(a, bfr[nt], acc[mt][nt], 0, 0, 0); \
        }                                                                               \
    } else if (i == 128) {                                                              \
        _Pragma("unroll")                                                               \
        for (int mt = 0; mt < 4; ++mt) {                                                \
            int row = wm + mt * 16 + mrow;                                              \
            f16x8 a = *(const f16x8*)&Lt[row * 128 + ((((T) * 4 + q) ^ mrow) << 3)];    \
            _Pragma("unroll")                                                           \
            for (int nt = 0; nt < 4; ++nt)                                              \
                acc[mt][nt] = __builtin_amdgcn_mfma_f32_16x16x32_f16(a, bfr[nt], acc[mt][nt], 0, 0, 0); \
        }                                                                               \
    } else {                                                                            \
        _Pragma("unroll")                                                               \
        for (int mt = 0; mt < 4; ++mt) {                                                \
            f16x8 a = rf[mt][T];                                                        \
            _Pragma("unroll")                                                           \
            for (int nt = 0; nt < 4; ++nt)                                              \
                acc[mt][nt] = __builtin_amdgcn_mfma_f32_16x16x32_f16(a, bfr[nt], acc[mt][nt], 0, 0, 0); \
        }                                                                               \
    } }

    for (int st = 0; st < NS; ++st) {
        if (st + 1 < NS) stage(imap((st + 1) >> 1), (st + 1) & 1, (st + 1) & 1);
        const int i   = imap(st >> 1);
        const int buf = st & 1;
        if ((st & 1) == 0) {
            if (i < 128) {
                #pragma unroll
                for (int mt = 0; mt < 4; ++mt) {
                    f16 lv = Lt[(wm + mt * 16 + mrow) * 128 + (((i >> 3) ^ mrow) << 3) + (i & 7)];
                    #pragma unroll
                    for (int e = 0; e < 8; ++e) lp[mt][e] = lv;
                }
            }
            TSTEP(0); TSTEP(1);
        } else {
            TSTEP(2); TSTEP(3);
        }
        __syncthreads();
    }
#undef TSTEP

    float* pb = part + ((size_t)s * Mrows + m0) * DD;
    #pragma unroll
    for (int mt = 0; mt < 4; ++mt)
        #pragma unroll
        for (int nt = 0; nt < 4; ++nt) {
            int colg = wn + nt * 16 + mrow;
            #pragma unroll
            for (int r = 0; r < 4; ++r) {
                int rowl = wm + mt * 16 + q * 4 + r;
                pb[(size_t)rowl * DD + colg] = acc[mt][nt][r];
            }
        }
}

// ---------------------------------------------------------------------------
__global__ void epi_level(const float* __restrict__ part, const float* __restrict__ bias,
                          f16* __restrict__ hout, int Mrows, int S)
{
    int idx = (blockIdx.x * 256 + threadIdx.x) * 4;
    size_t stride = (size_t)Mrows * DD;
    f32x4 sum = *(const f32x4*)&part[idx];
    for (int s2 = 1; s2 < S; ++s2)
        sum += *(const f32x4*)&part[(size_t)s2 * stride + idx];
    int n = idx & 127;
    f16 o[4];
    #pragma unroll
    for (int e = 0; e < 4; ++e) o[e] = (f16)tanhf(sum[e] + bias[n + e]);
    *(unsigned long long*)&hout[idx] = *(unsigned long long*)o;
}

// ---------------------------------------------------------------------------
__global__ void fin_epi(const float* __restrict__ part, const float* __restrict__ bias,
                        const float* __restrict__ Wsm_f, const float* __restrict__ bsm_f,
                        const int* __restrict__ flag, void* __restrict__ outp, int S)
{
    int lane = threadIdx.x & 63;
    int wv = threadIdx.x >> 6;
    int p = blockIdx.x * 4 + wv;              // 0..511
    size_t stride = (size_t)512 * DD;
    const float* base = part + (size_t)p * DD;
    float a0 = 0.f, a1 = 0.f;
    for (int s2 = 0; s2 < S; ++s2) {
        a0 += base[(size_t)s2 * stride + lane];
        a1 += base[(size_t)s2 * stride + 64 + lane];
    }
    a0 += bias[lane];      a1 += bias[64 + lane];
    a0 = (a0 > 0.f) ? a0 : 0.01f * a0;
    a1 = (a1 > 0.f) ? a1 : 0.01f * a1;
    float lg[NRELS];
    #pragma unroll
    for (int r = 0; r < NRELS; ++r) {
        float pr = a0 * Wsm_f[r * DD + lane] + a1 * Wsm_f[r * DD + 64 + lane];
        #pragma unroll
        for (int d = 1; d < 64; d <<= 1) pr += __shfl_xor(pr, d, 64);
        lg[r] = pr + bsm_f[r];
    }
    float mx = lg[0];
    #pragma unroll
    for (int r = 1; r < NRELS; ++r) mx = fmaxf(mx, lg[r]);
    float se = 0.f;
    #pragma unroll
    for (int r = 0; r < NRELS; ++r) se += expf(lg[r] - mx);
    float lse = logf(se) + mx;
    if (lane < NRELS) {
        float v = lg[lane] - lse;
        if (*flag) ((__hip_bfloat16*)outp)[p * NRELS + lane] = __float2bfloat16(v);
        else       ((float*)outp)[p * NRELS + lane] = v;
    }
}

// ---------------------------------------------------------------------------
extern "C" void kernel_launch(void* const* d_in, const int* in_sizes, int n_in,
                              void* d_out, int out_size, void* d_ws, size_t ws_size,
                              hipStream_t stream)
{
    const int* ids = (const int*)d_in[0];

    char* ws = (char*)d_ws;
    float* part     = (float*)ws;                                    // 16 MB max
    f16*   h0       = (f16*)(ws + ((size_t)16 << 20));               // 4 MB
    f16*   h1       = (f16*)(ws + ((size_t)20 << 20));               // 2 MB
    f16*   h2       = (f16*)(ws + ((size_t)22 << 20));               // 1 MB
    f16*   h3       = (f16*)(ws + ((size_t)23 << 20));               // 0.5 MB
    f16*   h4       = (f16*)(ws + ((size_t)23 << 20) + (512 << 10)); // 0.25 MB
    f16*   WvT      = (f16*)(ws + ((size_t)24 << 20));               // 0.5 MB
    f16*   Wext     = (f16*)(ws + ((size_t)24 << 20) + (512 << 10)); // 4.0625 MB
    f16*   Wfin     = Wext + (size_t)DD * KW;                        // 4.0625 MB
    float* bias_lvl = (float*)(Wfin + (size_t)DD * KW);
    float* bias_fin = bias_lvl + 128;
    int*   flag     = (int*)(bias_fin + 128);
    float* Wsm_f    = (float*)(flag + 16);
    float* bsm_f    = Wsm_f + NRELS * DD;

    if (ws_size < ((size_t)34 << 20)) return;

    detect_kernel<<<1, 64, 0, stream>>>((const unsigned short*)d_in[1], flag);
    prep_kernel<<<17669, 256, 0, stream>>>(d_in[1], d_in[2], d_in[3], d_in[4], d_in[5], d_in[6],
                                           d_in[7], d_in[8], d_in[9], d_in[10], d_in[11], d_in[12],
                                           flag, WvT, Wext, Wfin, bias_lvl, bias_fin, Wsm_f, bsm_f);
    embed_kernel<<<1024, 256, 0, stream>>>(ids, WvT, h0);

    gemm_kernel<<<64 * 4, 256, 0, stream>>>(h0, Wext, part, 8192, 4, 32);
    epi_level<<<1024, 256, 0, stream>>>(part, bias_lvl, h1, 8192, 4);
    gemm_kernel<<<32 * 8, 256, 0, stream>>>(h1, Wext, part, 4096, 8, 16);
    epi_level<<<512, 256, 0, stream>>>(part, bias_lvl, h2, 4096, 8);
    gemm_kernel<<<16 * 16, 256, 0, stream>>>(h2, Wext, part, 2048, 16, 8);
    epi_level<<<256, 256, 0, stream>>>(part, bias_lvl, h3, 2048, 16);
    gemm_kernel<<<8 * 32, 256, 0, stream>>>(h3, Wext, part, 1024, 32, 4);
    epi_level<<<128, 256, 0, stream>>>(part, bias_lvl, h4, 1024, 32);
    gemm_kernel<<<4 * 64, 256, 0, stream>>>(h4, Wfin, part, 512, 64, 2);
    fin_epi<<<128, 256, 0, stream>>>(part, bias_fin, Wsm_f, bsm_f, flag, d_out, 64);
}

// Round 3
// 309.043 us; speedup vs baseline: 1.2547x; 1.2547x over previous
//
#include <hip/hip_runtime.h>
#include <hip/hip_bf16.h>
#include <hip/hip_fp16.h>

#define DD    128
#define VOCAB 2048
#define NRELS 7
#define NWF   (130 * 16384)   // W frag-layout elements: 128 kron + l + r chunks

typedef _Float16 f16;
typedef __attribute__((ext_vector_type(8))) _Float16 f16x8;
typedef __attribute__((ext_vector_type(4))) float    f32x4;

// flexible-dtype load: bf==1 -> bf16 storage, bf==0 -> f32 storage
__device__ __forceinline__ float lde(const void* p, size_t i, int bf) {
    if (bf) return (float)((const __hip_bfloat16*)p)[i];
    return ((const float*)p)[i];
}

// ---------------------------------------------------------------------------
// detect storage dtype by exponent-field sanity (see R1 notes)
// ---------------------------------------------------------------------------
__global__ void detect_kernel(const unsigned short* __restrict__ wv, int* __restrict__ flag)
{
    if (threadIdx.x == 0 && blockIdx.x == 0) {
        int sane = 0;
        for (int i = 0; i < 64; ++i) {
            unsigned e = (wv[i] >> 7) & 0xFFu;
            if (e >= 90u && e <= 160u) ++sane;
        }
        *flag = (sane == 64) ? 1 : 0;
    }
}

// ---------------------------------------------------------------------------
// prep: f16 working copies. W stored FRAGMENT-MAJOR:
//   Wf[idx], idx = ((i*8 + n8)*4 + t)*512 + lane*8 + e
//   maps to W[n = n8*16 + (lane&15)][k = i*128 + t*32 + (lane>>4)*8 + e]
//   chunk i<128: Wcpst column-block i; i=128: Wcps l-half; i=129: Wcps r-half.
// ---------------------------------------------------------------------------
__global__ void prep_kernel(const void* Wv, const void* bv, const void* Wcps, const void* bcps,
                            const void* Wcpst, const void* bcpst, const void* Wcpr, const void* bcpr,
                            const void* Wcprt, const void* bcprt, const void* Wsm, const void* bsm,
                            const int* __restrict__ flag,
                            f16* __restrict__ WvT, f16* __restrict__ Wext, f16* __restrict__ Wfin,
                            float* __restrict__ bias_lvl, float* __restrict__ bias_fin,
                            float* __restrict__ Wsm_f, float* __restrict__ bsm_f)
{
    const int bf = *flag;
    long idx = (long)blockIdx.x * 256 + threadIdx.x;
    const long nWvT = (long)VOCAB * DD;        // 262144
    if (idx < nWvT) {
        int v = (int)(idx >> 7), d = (int)(idx & 127);
        WvT[idx] = (f16)(lde(Wv, (size_t)d * VOCAB + v, bf) + lde(bv, d, bf));
        return;
    }
    idx -= nWvT;
    if (idx < 2 * (long)NWF) {
        f16* dst = (idx < NWF) ? Wext : Wfin;
        const void* Wt = (idx < NWF) ? Wcpst : Wcprt;   // kron weights
        const void* Ws = (idx < NWF) ? Wcps  : Wcpr;    // linear weights
        long id2 = (idx < NWF) ? idx : idx - NWF;
        int i   = (int)(id2 >> 14);
        int rem = (int)(id2 & 16383);
        int n8  = rem >> 11;
        int t   = (rem >> 9) & 3;
        int ln  = (rem >> 3) & 63;
        int e   = rem & 7;
        int nn   = n8 * 16 + (ln & 15);
        int koff = t * 32 + ((ln >> 4) << 3) + e;       // 0..127
        float val = (i < 128) ? lde(Wt, (size_t)nn * 16384 + (size_t)i * 128 + koff, bf)
                              : lde(Ws, (size_t)nn * 256 + (size_t)(i - 128) * 128 + koff, bf);
        dst[id2] = (f16)val;
        return;
    }
    idx -= 2 * (long)NWF;
    if (idx < 128)            bias_lvl[idx] = lde(bcps, idx, bf) + lde(bcpst, idx, bf);
    else if (idx < 256)       bias_fin[idx - 128] = lde(bcpr, idx - 128, bf) + lde(bcprt, idx - 128, bf);
    else if (idx < 256 + 896) Wsm_f[idx - 256] = lde(Wsm, idx - 256, bf);
    else if (idx < 256 + 896 + NRELS) bsm_f[idx - 256 - 896] = lde(bsm, idx - 256 - 896, bf);
}

// ---------------------------------------------------------------------------
__global__ void embed_kernel(const int* __restrict__ ids,
                             const f16* __restrict__ WvT, f16* __restrict__ h0)
{
    int t = blockIdx.x * 256 + threadIdx.x;
    int row = t >> 4;
    int c = (t & 15) * 8;
    int id = ids[row];
    *(f16x8*)&h0[(size_t)row * DD + c] = *(const f16x8*)&WvT[(size_t)id * DD + c];
}

// ---------------------------------------------------------------------------
// GEMM over A_ext = [kron(l,r) | l | r] vs W (128 x 16640), split-K over kron
// rows i. Block = 64 merge-rows x 128 n, 2 waves (each 64x64). No barriers in
// the K-loop: W streams global->regs from frag-major layout, 1 stage ahead.
// Partials stored f16 -> part[s][p][n].
// ---------------------------------------------------------------------------
__launch_bounds__(128, 2)
__global__ void gemm_kernel(const f16* __restrict__ hin, const f16* __restrict__ Wf,
                            f16* __restrict__ part, int Mrows, int S, int BI)
{
    __shared__ f16 Lt[64 * 128];        // 16 KB, phys 8-half block = cb ^ (row&15)

    const int tid  = threadIdx.x;
    const int lane = tid & 63;
    const int wv   = tid >> 6;
    const int s    = blockIdx.x % S;
    const int mb   = blockIdx.x / S;
    const int m0   = mb * 64;
    const int i0   = s * BI;
    const int nI   = BI + ((s == 0) ? 2 : 0);
    const int NSt  = nI * 4;

    // ---- stage Lt (l rows = even input rows), swizzled 8-half blocks ----
    #pragma unroll
    for (int it = 0; it < 8; ++it) {
        int c  = it * 128 + tid;            // 0..1023
        int mm = c >> 4;                    // 0..63
        int cb = c & 15;
        f16x8 v = *(const f16x8*)&hin[(size_t)(2 * (m0 + mm)) * DD + cb * 8];
        *(f16x8*)&Lt[mm * 128 + ((cb ^ (mm & 15)) << 3)] = v;
    }

    const int mrow = lane & 15;
    const int q    = lane >> 4;

    // ---- r fragments into registers (reused across all i) ----
    f16x8 rf[4][4];
    #pragma unroll
    for (int mt = 0; mt < 4; ++mt)
        #pragma unroll
        for (int t = 0; t < 4; ++t)
            rf[mt][t] = *(const f16x8*)&hin[(size_t)(2 * (m0 + mt * 16 + mrow) + 1) * DD + t * 32 + q * 8];

    __syncthreads();

    auto imap = [&](int ii) { return (ii < BI) ? (i0 + ii) : (128 + ii - BI); };
    const f16* wb0 = Wf + wv * 8192 + lane * 8;
    auto ldW = [&](int st, f16x8* d) {
        int i = imap(st >> 2), t = st & 3;
        const f16* p = wb0 + (size_t)i * 16384 + t * 512;
        #pragma unroll
        for (int nt = 0; nt < 4; ++nt) d[nt] = *(const f16x8*)(p + nt * 2048);
    };
    auto lpRead = [&](int i, int mt) -> f16 {
        return Lt[(mt * 16 + mrow) * 128 + (((i >> 3) ^ mrow) << 3) + (i & 7)];
    };

    f32x4 acc[4][4] = {};
    f16x8 wbuf[2][4];
    f16 lpv[4], lpn[4];

    ldW(0, wbuf[0]);
    {
        int i = imap(0);
        if (i < 128) {
            #pragma unroll
            for (int mt = 0; mt < 4; ++mt) lpv[mt] = lpRead(i, mt);
        }
    }

    for (int ii = 0; ii < nI; ++ii) {
        const int i = imap(ii);
        f16x8 lb[4];
        if (i < 128) {
            #pragma unroll
            for (int mt = 0; mt < 4; ++mt) {
                f16 v = lpv[mt];
                #pragma unroll
                for (int e = 0; e < 8; ++e) lb[mt][e] = v;
            }
        }
        #pragma unroll
        for (int t = 0; t < 4; ++t) {
            const int st = ii * 4 + t;
            if (st + 1 < NSt) ldW(st + 1, wbuf[(t + 1) & 1]);
            if (t == 1 && ii + 1 < nI) {
                int i2 = imap(ii + 1);
                if (i2 < 128) {
                    #pragma unroll
                    for (int mt = 0; mt < 4; ++mt) lpn[mt] = lpRead(i2, mt);
                }
            }
            const f16x8* wc = wbuf[t & 1];
            if (i < 128) {
                #pragma unroll
                for (int mt = 0; mt < 4; ++mt) {
                    f16x8 a = lb[mt] * rf[mt][t];
                    #pragma unroll
                    for (int nt = 0; nt < 4; ++nt)
                        acc[mt][nt] = __builtin_amdgcn_mfma_f32_16x16x32_f16(a, wc[nt], acc[mt][nt], 0, 0, 0);
                }
            } else if (i == 128) {
                #pragma unroll
                for (int mt = 0; mt < 4; ++mt) {
                    f16x8 a = *(const f16x8*)&Lt[(mt * 16 + mrow) * 128 + (((t * 4 + q) ^ mrow) << 3)];
                    #pragma unroll
                    for (int nt = 0; nt < 4; ++nt)
                        acc[mt][nt] = __builtin_amdgcn_mfma_f32_16x16x32_f16(a, wc[nt], acc[mt][nt], 0, 0, 0);
                }
            } else {
                #pragma unroll
                for (int mt = 0; mt < 4; ++mt) {
                    #pragma unroll
                    for (int nt = 0; nt < 4; ++nt)
                        acc[mt][nt] = __builtin_amdgcn_mfma_f32_16x16x32_f16(rf[mt][t], wc[nt], acc[mt][nt], 0, 0, 0);
                }
            }
        }
        #pragma unroll
        for (int mt = 0; mt < 4; ++mt) lpv[mt] = lpn[mt];
    }

    // ---- store f16 partial tile: C/D layout col=lane&15, row=q*4+reg ----
    f16* pb = part + ((size_t)s * Mrows + m0) * DD;
    #pragma unroll
    for (int mt = 0; mt < 4; ++mt)
        #pragma unroll
        for (int nt = 0; nt < 4; ++nt) {
            int colg = wv * 64 + nt * 16 + mrow;
            #pragma unroll
            for (int r = 0; r < 4; ++r) {
                int rowl = mt * 16 + q * 4 + r;
                pb[(size_t)rowl * DD + colg] = (f16)acc[mt][nt][r];
            }
        }
}

// ---------------------------------------------------------------------------
// level epilogue: h_out = f16(tanh(sum_s part[s] + bias))
// ---------------------------------------------------------------------------
__global__ void epi_level(const f16* __restrict__ part, const float* __restrict__ bias,
                          f16* __restrict__ hout, int Mrows, int S)
{
    int idx = (blockIdx.x * 256 + threadIdx.x) * 8;
    size_t stride = (size_t)Mrows * DD;
    float sum[8] = {};
    for (int s2 = 0; s2 < S; ++s2) {
        f16x8 v = *(const f16x8*)&part[(size_t)s2 * stride + idx];
        #pragma unroll
        for (int e = 0; e < 8; ++e) sum[e] += (float)v[e];
    }
    int n = idx & 127;
    f16x8 o;
    #pragma unroll
    for (int e = 0; e < 8; ++e) o[e] = (f16)tanhf(sum[e] + bias[n + e]);
    *(f16x8*)&hout[idx] = o;
}

// ---------------------------------------------------------------------------
// final epilogue: leaky_relu(sum_s part + bias) @ Wsm^T + bsm -> log_softmax
// ---------------------------------------------------------------------------
__global__ void fin_epi(const f16* __restrict__ part, const float* __restrict__ bias,
                        const float* __restrict__ Wsm_f, const float* __restrict__ bsm_f,
                        const int* __restrict__ flag, void* __restrict__ outp, int S)
{
    int lane = threadIdx.x & 63;
    int wv = threadIdx.x >> 6;
    int p = blockIdx.x * 4 + wv;              // 0..511
    size_t stride = (size_t)512 * DD;
    const f16* base = part + (size_t)p * DD;
    float a0 = 0.f, a1 = 0.f;
    for (int s2 = 0; s2 < S; ++s2) {
        a0 += (float)base[(size_t)s2 * stride + lane];
        a1 += (float)base[(size_t)s2 * stride + 64 + lane];
    }
    a0 += bias[lane];      a1 += bias[64 + lane];
    a0 = (a0 > 0.f) ? a0 : 0.01f * a0;
    a1 = (a1 > 0.f) ? a1 : 0.01f * a1;
    float lg[NRELS];
    #pragma unroll
    for (int r = 0; r < NRELS; ++r) {
        float pr = a0 * Wsm_f[r * DD + lane] + a1 * Wsm_f[r * DD + 64 + lane];
        #pragma unroll
        for (int d = 1; d < 64; d <<= 1) pr += __shfl_xor(pr, d, 64);
        lg[r] = pr + bsm_f[r];
    }
    float mx = lg[0];
    #pragma unroll
    for (int r = 1; r < NRELS; ++r) mx = fmaxf(mx, lg[r]);
    float se = 0.f;
    #pragma unroll
    for (int r = 0; r < NRELS; ++r) se += expf(lg[r] - mx);
    float lse = logf(se) + mx;
    if (lane < NRELS) {
        float v = lg[lane] - lse;
        if (*flag) ((__hip_bfloat16*)outp)[p * NRELS + lane] = __float2bfloat16(v);
        else       ((float*)outp)[p * NRELS + lane] = v;
    }
}

// ---------------------------------------------------------------------------
extern "C" void kernel_launch(void* const* d_in, const int* in_sizes, int n_in,
                              void* d_out, int out_size, void* d_ws, size_t ws_size,
                              hipStream_t stream)
{
    const int* ids = (const int*)d_in[0];

    char* ws = (char*)d_ws;
    f16*   part     = (f16*)ws;                                      // 16 MiB region (f16 partials)
    f16*   h0       = (f16*)(ws + ((size_t)16 << 20));               // 4 MiB
    f16*   h1       = (f16*)(ws + ((size_t)20 << 20));               // 2 MiB
    f16*   h2       = (f16*)(ws + ((size_t)22 << 20));               // 1 MiB
    f16*   h3       = (f16*)(ws + ((size_t)23 << 20));               // 0.5 MiB
    f16*   h4       = (f16*)(ws + ((size_t)23 << 20) + (512 << 10)); // 0.25 MiB
    f16*   WvT      = (f16*)(ws + ((size_t)24 << 20));               // 0.5 MiB
    f16*   Wext     = (f16*)(ws + ((size_t)24 << 20) + (512 << 10)); // 4.0625 MiB
    f16*   Wfin     = Wext + (size_t)NWF;                            // 4.0625 MiB
    float* bias_lvl = (float*)(Wfin + (size_t)NWF);
    float* bias_fin = bias_lvl + 128;
    int*   flag     = (int*)(bias_fin + 128);
    float* Wsm_f    = (float*)(flag + 16);
    float* bsm_f    = Wsm_f + NRELS * DD;

    if (ws_size < ((size_t)34 << 20)) return;

    detect_kernel<<<1, 64, 0, stream>>>((const unsigned short*)d_in[1], flag);
    prep_kernel<<<17669, 256, 0, stream>>>(d_in[1], d_in[2], d_in[3], d_in[4], d_in[5], d_in[6],
                                           d_in[7], d_in[8], d_in[9], d_in[10], d_in[11], d_in[12],
                                           flag, WvT, Wext, Wfin, bias_lvl, bias_fin, Wsm_f, bsm_f);
    embed_kernel<<<1024, 256, 0, stream>>>(ids, WvT, h0);

    // level 1: M=8192 (128 tiles) x S=8 -> 1024 blocks
    gemm_kernel<<<1024, 128, 0, stream>>>(h0, Wext, part, 8192, 8, 16);
    epi_level<<<512, 256, 0, stream>>>(part, bias_lvl, h1, 8192, 8);
    // level 2: M=4096 (64) x S=16 -> 1024
    gemm_kernel<<<1024, 128, 0, stream>>>(h1, Wext, part, 4096, 16, 8);
    epi_level<<<256, 256, 0, stream>>>(part, bias_lvl, h2, 4096, 16);
    // level 3: M=2048 (32) x S=32 -> 1024
    gemm_kernel<<<1024, 128, 0, stream>>>(h2, Wext, part, 2048, 32, 4);
    epi_level<<<128, 256, 0, stream>>>(part, bias_lvl, h3, 2048, 32);
    // level 4: M=1024 (16) x S=64 -> 1024
    gemm_kernel<<<1024, 128, 0, stream>>>(h3, Wext, part, 1024, 64, 2);
    epi_level<<<64, 256, 0, stream>>>(part, bias_lvl, h4, 1024, 64);
    // final: M=512 (8) x S=128 -> 1024
    gemm_kernel<<<1024, 128, 0, stream>>>(h4, Wfin, part, 512, 128, 1);
    fin_epi<<<128, 256, 0, stream>>>(part, bias_fin, Wsm_f, bsm_f, flag, d_out, 128);
}